// Round 1
// baseline (695.492 us; speedup 1.0000x reference)
//
#include <hip/hip_runtime.h>

#define MM 1024
#define NE 100000
#define KD 256
#define BM 128
#define BN 128
#define BK 64

typedef __attribute__((ext_vector_type(8))) short bf16x8;
typedef __attribute__((ext_vector_type(4))) float f32x4;
typedef __attribute__((ext_vector_type(4))) short short4v;

// ws layout (bytes):
//   [0, 524288)        hr bf16   1024*256*2
//   [524288, 528384)   hr_sq f32 1024
//   [528384, 928384)   ent_sq f32 100000
//   [928384, 936576)   packed argmax u64 x 1024
#define WS_HRSQ   524288
#define WS_ENTSQ  528384
#define WS_PACKED 928384

__device__ __forceinline__ unsigned short f2bf(float f) {
    union { float f; unsigned int u; } v; v.f = f;
    unsigned int u = v.u;
    return (unsigned short)((u + 0x7FFFu + ((u >> 16) & 1u)) >> 16);
}

__device__ __forceinline__ bf16x8 pack8(float4 a, float4 b) {
    bf16x8 t;
    t[0] = (short)f2bf(a.x); t[1] = (short)f2bf(a.y);
    t[2] = (short)f2bf(a.z); t[3] = (short)f2bf(a.w);
    t[4] = (short)f2bf(b.x); t[5] = (short)f2bf(b.y);
    t[6] = (short)f2bf(b.z); t[7] = (short)f2bf(b.w);
    return t;
}

// ---- prep: hr = E[head] + R[rel]; hr bf16; hr_sq; init packed argmax ----
__global__ __launch_bounds__(64) void prep_kernel(const int* __restrict__ q,
                                                  const float* __restrict__ ent,
                                                  const float* __restrict__ rel,
                                                  unsigned short* __restrict__ hrb,
                                                  float* __restrict__ hrsq,
                                                  unsigned long long* __restrict__ packed) {
    int b = blockIdx.x;
    int lane = threadIdx.x;
    int head = q[b * 3 + 0];
    int r    = q[b * 3 + 1];
    float4 e  = ((const float4*)(ent + (size_t)head * KD))[lane];
    float4 rv = ((const float4*)(rel + (size_t)r * KD))[lane];
    float4 h; h.x = e.x + rv.x; h.y = e.y + rv.y; h.z = e.z + rv.z; h.w = e.w + rv.w;
    short4v hv;
    hv[0] = (short)f2bf(h.x); hv[1] = (short)f2bf(h.y);
    hv[2] = (short)f2bf(h.z); hv[3] = (short)f2bf(h.w);
    *(short4v*)(hrb + (size_t)b * KD + lane * 4) = hv;
    float sq = h.x * h.x + h.y * h.y + h.z * h.z + h.w * h.w;
    #pragma unroll
    for (int off = 32; off > 0; off >>= 1) sq += __shfl_down(sq, off, 64);
    if (lane == 0) { hrsq[b] = sq; packed[b] = 0ull; }
}

// ---- ent_sq: per-entity squared norm (one wave per row) ----
__global__ __launch_bounds__(256) void entsq_kernel(const float* __restrict__ ent,
                                                    float* __restrict__ entsq) {
    int w = threadIdx.x >> 6, lane = threadIdx.x & 63;
    int n = blockIdx.x * 4 + w;
    if (n >= NE) return;
    float4 v = ((const float4*)(ent + (size_t)n * KD))[lane];
    float s = v.x * v.x + v.y * v.y + v.z * v.z + v.w * v.w;
    #pragma unroll
    for (int off = 32; off > 0; off >>= 1) s += __shfl_down(s, off, 64);
    if (lane == 0) entsq[n] = s;
}

// ---- GEMM: scores = 2*(hr . E^T) - hr_sq - ent_sq, fused argmax ----
__global__ __launch_bounds__(256) void gemm_kernel(const unsigned short* __restrict__ hrb,
                                                   const float* __restrict__ ent,
                                                   const float* __restrict__ hrsq,
                                                   const float* __restrict__ entsq,
                                                   float* __restrict__ out,
                                                   unsigned long long* __restrict__ packed) {
    __shared__ __align__(16) unsigned short As[BM * BK];
    __shared__ __align__(16) unsigned short Bs[BN * BK];

    const int tid  = threadIdx.x;
    const int lane = tid & 63;
    const int wid  = tid >> 6;
    const int wr = wid >> 1, wc = wid & 1;
    const int n0 = blockIdx.x * BN;
    const int m0 = blockIdx.y * BM;

    f32x4 acc[4][4];
    #pragma unroll
    for (int m = 0; m < 4; ++m)
        #pragma unroll
        for (int n = 0; n < 4; ++n)
            acc[m][n] = (f32x4){0.f, 0.f, 0.f, 0.f};

    // staging mapping: thread -> (row, half); each thread moves 32 elems/tile
    const int srow  = tid >> 1;
    const int shalf = tid & 1;
    const unsigned short* agp = hrb + (size_t)(m0 + srow) * KD + shalf * 32;
    int ng = n0 + srow;
    const bool nvalid = ng < NE;
    const float* bgp = ent + (size_t)(nvalid ? ng : 0) * KD + shalf * 32;

    for (int kt = 0; kt < KD / BK; ++kt) {
        __syncthreads();
        // stage A (bf16 from ws), swizzled: byte ^= (row&7)<<4
        #pragma unroll
        for (int j = 0; j < 4; ++j) {
            bf16x8 t = *(const bf16x8*)(agp + kt * BK + j * 8);
            int col = shalf * 32 + j * 8;
            int byte = ((srow * BK + col) * 2) ^ ((srow & 7) << 4);
            *(bf16x8*)((char*)As + byte) = t;
        }
        // stage B (f32 global -> bf16), swizzled
        {
            const float4* bp = (const float4*)(bgp + kt * BK);
            float4 v[8];
            #pragma unroll
            for (int j = 0; j < 8; ++j) {
                float4 t = bp[j];
                if (!nvalid) { t.x = 0.f; t.y = 0.f; t.z = 0.f; t.w = 0.f; }
                v[j] = t;
            }
            #pragma unroll
            for (int j = 0; j < 4; ++j) {
                bf16x8 t = pack8(v[2 * j], v[2 * j + 1]);
                int col = shalf * 32 + j * 8;
                int byte = ((srow * BK + col) * 2) ^ ((srow & 7) << 4);
                *(bf16x8*)((char*)Bs + byte) = t;
            }
        }
        __syncthreads();
        // compute
        #pragma unroll
        for (int ks = 0; ks < 2; ++ks) {
            const int kc = ks * 32 + (lane >> 4) * 8;
            bf16x8 af[4], bfr[4];
            #pragma unroll
            for (int m = 0; m < 4; ++m) {
                int r = wr * 64 + m * 16 + (lane & 15);
                int byte = ((r * BK + kc) * 2) ^ ((r & 7) << 4);
                af[m] = *(const bf16x8*)((char*)As + byte);
            }
            #pragma unroll
            for (int n = 0; n < 4; ++n) {
                int r = wc * 64 + n * 16 + (lane & 15);
                int byte = ((r * BK + kc) * 2) ^ ((r & 7) << 4);
                bfr[n] = *(const bf16x8*)((char*)Bs + byte);
            }
            #pragma unroll
            for (int m = 0; m < 4; ++m)
                #pragma unroll
                for (int n = 0; n < 4; ++n)
                    acc[m][n] = __builtin_amdgcn_mfma_f32_16x16x32_bf16(af[m], bfr[n], acc[m][n], 0, 0, 0);
        }
    }

    // epilogue: scores + fused per-row argmax
    int   cg[4];
    float eq[4];
    #pragma unroll
    for (int n = 0; n < 4; ++n) {
        cg[n] = n0 + wc * 64 + n * 16 + (lane & 15);
        eq[n] = (cg[n] < NE) ? entsq[cg[n]] : 0.f;
    }

    #pragma unroll
    for (int m = 0; m < 4; ++m) {
        #pragma unroll
        for (int j = 0; j < 4; ++j) {
            int rl = wr * 64 + m * 16 + ((lane >> 4) << 2) + j;
            int rg = m0 + rl;
            float hq = hrsq[rg];
            size_t ro = (size_t)rg * NE;
            unsigned long long best = 0ull;
            #pragma unroll
            for (int n = 0; n < 4; ++n) {
                if (cg[n] < NE) {
                    float s = 2.0f * acc[m][n][j] - hq - eq[n];
                    out[ro + cg[n]] = s;
                    unsigned int u = __float_as_uint(s);
                    unsigned int key = u ^ ((unsigned int)((int)u >> 31) | 0x80000000u);
                    unsigned long long k64 =
                        ((unsigned long long)key << 32) | (unsigned int)(~cg[n]);
                    best = (k64 > best) ? k64 : best;
                }
            }
            #pragma unroll
            for (int off = 8; off > 0; off >>= 1) {
                unsigned long long o =
                    (unsigned long long)__shfl_xor((long long)best, off, 16);
                best = (o > best) ? o : best;
            }
            if ((lane & 15) == 0) atomicMax(packed + rg, best);
        }
    }
}

// ---- finalize: unpack argmax col, store as float ----
__global__ __launch_bounds__(256) void final_kernel(const unsigned long long* __restrict__ packed,
                                                    float* __restrict__ pred) {
    int b = blockIdx.x * 256 + threadIdx.x;
    if (b < MM) {
        unsigned int ic = (unsigned int)(packed[b] & 0xFFFFFFFFull);
        pred[b] = (float)(~ic);
    }
}

extern "C" void kernel_launch(void* const* d_in, const int* in_sizes, int n_in,
                              void* d_out, int out_size, void* d_ws, size_t ws_size,
                              hipStream_t stream) {
    const int*   q   = (const int*)d_in[0];
    const float* ent = (const float*)d_in[1];
    const float* rel = (const float*)d_in[2];
    float* out = (float*)d_out;
    char*  ws  = (char*)d_ws;

    unsigned short*     hrb    = (unsigned short*)ws;
    float*              hrsq   = (float*)(ws + WS_HRSQ);
    float*              entsq  = (float*)(ws + WS_ENTSQ);
    unsigned long long* packed = (unsigned long long*)(ws + WS_PACKED);
    float* pred = out + (size_t)MM * NE;

    prep_kernel<<<MM, 64, 0, stream>>>(q, ent, rel, hrb, hrsq, packed);
    entsq_kernel<<<(NE + 3) / 4, 256, 0, stream>>>(ent, entsq);
    gemm_kernel<<<dim3((NE + BN - 1) / BN, MM / BM), 256, 0, stream>>>(hrb, ent, hrsq, entsq, out, packed);
    final_kernel<<<(MM + 255) / 256, 256, 0, stream>>>(packed, pred);
}

// Round 2
// 392.826 us; speedup vs baseline: 1.7705x; 1.7705x over previous
//
#include <hip/hip_runtime.h>

#define MM 1024
#define NE 100000
#define KD 256
#define NT 782   // ceil(NE/128)
#define MT 8     // 1024/128

typedef __attribute__((ext_vector_type(8))) short bf16x8;
typedef __attribute__((ext_vector_type(4))) float f32x4;
typedef __attribute__((ext_vector_type(4))) short short4v;

// ws layout (bytes):
//   [0, 524288)          hr bf16      1024*256*2
//   [524288, 528384)     hr_sq f32    1024
//   [528384, 928384)     ent_sq f32   100000
//   [928384, 936576)     packed u64   1024
//   [1048576, +51.2MB)   ent bf16     100000*256*2   (only if ws_size allows)
#define WS_HRSQ   524288
#define WS_ENTSQ  528384
#define WS_PACKED 928384
#define WS_ENTB   1048576
#define WS_NEED   (WS_ENTB + (size_t)NE * KD * 2)

__device__ __forceinline__ unsigned short f2bf(float f) {
    union { float f; unsigned int u; } v; v.f = f;
    unsigned int u = v.u;
    return (unsigned short)((u + 0x7FFFu + ((u >> 16) & 1u)) >> 16);
}

__device__ __forceinline__ bf16x8 pack8(float4 a, float4 b) {
    bf16x8 t;
    t[0] = (short)f2bf(a.x); t[1] = (short)f2bf(a.y);
    t[2] = (short)f2bf(a.z); t[3] = (short)f2bf(a.w);
    t[4] = (short)f2bf(b.x); t[5] = (short)f2bf(b.y);
    t[6] = (short)f2bf(b.z); t[7] = (short)f2bf(b.w);
    return t;
}

// ---- prep: hr = E[head] + R[rel] -> bf16; hr_sq; init packed argmax ----
__global__ __launch_bounds__(64) void prep_kernel(const int* __restrict__ q,
                                                  const float* __restrict__ ent,
                                                  const float* __restrict__ rel,
                                                  unsigned short* __restrict__ hrb,
                                                  float* __restrict__ hrsq,
                                                  unsigned long long* __restrict__ packed) {
    int b = blockIdx.x;
    int lane = threadIdx.x;
    int head = q[b * 3 + 0];
    int r    = q[b * 3 + 1];
    float4 e  = ((const float4*)(ent + (size_t)head * KD))[lane];
    float4 rv = ((const float4*)(rel + (size_t)r * KD))[lane];
    float4 h; h.x = e.x + rv.x; h.y = e.y + rv.y; h.z = e.z + rv.z; h.w = e.w + rv.w;
    short4v hv;
    hv[0] = (short)f2bf(h.x); hv[1] = (short)f2bf(h.y);
    hv[2] = (short)f2bf(h.z); hv[3] = (short)f2bf(h.w);
    *(short4v*)(hrb + (size_t)b * KD + lane * 4) = hv;
    float sq = h.x * h.x + h.y * h.y + h.z * h.z + h.w * h.w;
    #pragma unroll
    for (int off = 32; off > 0; off >>= 1) sq += __shfl_down(sq, off, 64);
    if (lane == 0) { hrsq[b] = sq; packed[b] = 0ull; }
}

// ---- fused: ent f32 -> bf16 + ent_sq. One half-wave per row, 2 rows/wave ----
__global__ __launch_bounds__(256) void conv_entsq_kernel(const float* __restrict__ ent,
                                                         unsigned short* __restrict__ entb,
                                                         float* __restrict__ entsq) {
    int gw   = (blockIdx.x * 256 + threadIdx.x) >> 6;   // global wave
    int lane = threadIdx.x & 63;
    int row  = gw * 2 + (lane >> 5);
    if (row >= NE) return;
    const float4* src = (const float4*)(ent + (size_t)row * KD) + (lane & 31) * 2;
    float4 a = src[0], b = src[1];
    *(bf16x8*)(entb + (size_t)row * KD + (lane & 31) * 8) = pack8(a, b);
    float s = a.x * a.x + a.y * a.y + a.z * a.z + a.w * a.w
            + b.x * b.x + b.y * b.y + b.z * b.z + b.w * b.w;
    #pragma unroll
    for (int off = 16; off > 0; off >>= 1) s += __shfl_xor(s, off, 64);
    if ((lane & 31) == 0) entsq[row] = s;
}

// ---- ent_sq only (fallback path) ----
__global__ __launch_bounds__(256) void entsq_kernel(const float* __restrict__ ent,
                                                    float* __restrict__ entsq) {
    int w = threadIdx.x >> 6, lane = threadIdx.x & 63;
    int n = blockIdx.x * 4 + w;
    if (n >= NE) return;
    float4 v = ((const float4*)(ent + (size_t)n * KD))[lane];
    float s = v.x * v.x + v.y * v.y + v.z * v.z + v.w * v.w;
    #pragma unroll
    for (int off = 32; off > 0; off >>= 1) s += __shfl_down(s, off, 64);
    if (lane == 0) entsq[n] = s;
}

// ---- fragment-direct GEMM, no LDS, fully unrolled K, fused argmax ----
// BF16B=1: B from pre-converted bf16 ws. BF16B=0: B from f32 entity directly.
template <int BF16B>
__global__ __launch_bounds__(256, 3) void gemm_direct(const unsigned short* __restrict__ hrb,
                                                      const unsigned short* __restrict__ entb,
                                                      const float* __restrict__ entf,
                                                      const float* __restrict__ hrsq,
                                                      const float* __restrict__ entsq,
                                                      float* __restrict__ out,
                                                      unsigned long long* __restrict__ packed) {
    const int bid  = blockIdx.x;
    // XCD-chunked swizzle: each XCD gets a contiguous n-slice covering all 8 m-tiles
    const int wgid = (bid & 7) * NT + (bid >> 3);
    const int mt = wgid & 7, nt = wgid >> 3;
    const int m0 = mt * 128, n0 = nt * 128;

    const int tid  = threadIdx.x;
    const int lane = tid & 63;
    const int wid  = tid >> 6;
    const int wr = wid >> 1, wc = wid & 1;
    const int lr = lane & 15;
    const int lk = (lane >> 4) * 8;   // k-offset (elems) of this lane's fragment slice

    const unsigned short* aP[4];
    const unsigned short* bP[4];
    const float*          bPf[4];
    int  cg[4];
    bool cv[4];
    #pragma unroll
    for (int i = 0; i < 4; ++i) {
        int ar = m0 + wr * 64 + i * 16 + lr;
        aP[i] = hrb + (size_t)ar * KD + lk;
        int nr = n0 + wc * 64 + i * 16 + lr;
        cg[i] = nr;
        cv[i] = nr < NE;
        int nrc = cv[i] ? nr : 0;
        bP[i]  = entb + (size_t)nrc * KD + lk;
        bPf[i] = entf + (size_t)nrc * KD + lk;
    }

    f32x4 acc[4][4];
    #pragma unroll
    for (int m = 0; m < 4; ++m)
        #pragma unroll
        for (int n = 0; n < 4; ++n)
            acc[m][n] = (f32x4){0.f, 0.f, 0.f, 0.f};

    #pragma unroll
    for (int ks = 0; ks < KD / 32; ++ks) {
        bf16x8 af[4], bfr[4];
        #pragma unroll
        for (int i = 0; i < 4; ++i)
            af[i] = *(const bf16x8*)(aP[i] + ks * 32);
        #pragma unroll
        for (int i = 0; i < 4; ++i) {
            if (BF16B) {
                bfr[i] = *(const bf16x8*)(bP[i] + ks * 32);
            } else {
                const float4* p = (const float4*)(bPf[i] + ks * 32);
                bfr[i] = pack8(p[0], p[1]);
            }
        }
        #pragma unroll
        for (int m = 0; m < 4; ++m)
            #pragma unroll
            for (int n = 0; n < 4; ++n)
                acc[m][n] = __builtin_amdgcn_mfma_f32_16x16x32_bf16(af[m], bfr[n], acc[m][n], 0, 0, 0);
    }

    // epilogue: scores = 2*cross - hr_sq - ent_sq, fused per-row argmax
    float eq[4];
    #pragma unroll
    for (int n = 0; n < 4; ++n) eq[n] = cv[n] ? entsq[cg[n]] : 0.f;

    #pragma unroll
    for (int m = 0; m < 4; ++m) {
        #pragma unroll
        for (int j = 0; j < 4; ++j) {
            int rg = m0 + wr * 64 + m * 16 + ((lane >> 4) << 2) + j;
            float hq = hrsq[rg];
            size_t ro = (size_t)rg * NE;
            unsigned long long best = 0ull;
            #pragma unroll
            for (int n = 0; n < 4; ++n) {
                if (cv[n]) {
                    float s = 2.0f * acc[m][n][j] - hq - eq[n];
                    out[ro + cg[n]] = s;
                    unsigned int u = __float_as_uint(s);
                    unsigned int key = u ^ ((unsigned int)((int)u >> 31) | 0x80000000u);
                    unsigned long long k64 =
                        ((unsigned long long)key << 32) | (unsigned int)(~cg[n]);
                    best = (k64 > best) ? k64 : best;
                }
            }
            #pragma unroll
            for (int off = 8; off > 0; off >>= 1) {
                unsigned long long o =
                    (unsigned long long)__shfl_xor((long long)best, off, 16);
                best = (o > best) ? o : best;
            }
            if ((lane & 15) == 0) atomicMax(packed + rg, best);
        }
    }
}

// ---- finalize: unpack argmax col, store as float ----
__global__ __launch_bounds__(256) void final_kernel(const unsigned long long* __restrict__ packed,
                                                    float* __restrict__ pred) {
    int b = blockIdx.x * 256 + threadIdx.x;
    if (b < MM) {
        unsigned int ic = (unsigned int)(packed[b] & 0xFFFFFFFFull);
        pred[b] = (float)(~ic);
    }
}

extern "C" void kernel_launch(void* const* d_in, const int* in_sizes, int n_in,
                              void* d_out, int out_size, void* d_ws, size_t ws_size,
                              hipStream_t stream) {
    const int*   q   = (const int*)d_in[0];
    const float* ent = (const float*)d_in[1];
    const float* rel = (const float*)d_in[2];
    float* out = (float*)d_out;
    char*  ws  = (char*)d_ws;

    unsigned short*     hrb    = (unsigned short*)ws;
    float*              hrsq   = (float*)(ws + WS_HRSQ);
    float*              entsq  = (float*)(ws + WS_ENTSQ);
    unsigned long long* packed = (unsigned long long*)(ws + WS_PACKED);
    unsigned short*     entb   = (unsigned short*)(ws + WS_ENTB);
    float* pred = out + (size_t)MM * NE;

    prep_kernel<<<MM, 64, 0, stream>>>(q, ent, rel, hrb, hrsq, packed);

    if (ws_size >= WS_NEED) {
        // 12500 blocks x 4 waves x 2 rows = 100000 rows exactly
        conv_entsq_kernel<<<12500, 256, 0, stream>>>(ent, entb, entsq);
        gemm_direct<1><<<MT * NT, 256, 0, stream>>>(hrb, entb, ent, hrsq, entsq, out, packed);
    } else {
        entsq_kernel<<<(NE + 3) / 4, 256, 0, stream>>>(ent, entsq);
        gemm_direct<0><<<MT * NT, 256, 0, stream>>>(hrb, entb, ent, hrsq, entsq, out, packed);
    }

    final_kernel<<<(MM + 255) / 256, 256, 0, stream>>>(packed, pred);
}

// Round 3
// 359.891 us; speedup vs baseline: 1.9325x; 1.0915x over previous
//
#include <hip/hip_runtime.h>

#define MM 1024
#define NE 100000
#define KD 256
#define NT 782   // ceil(NE/128)
#define MT 8     // 1024/128

typedef __attribute__((ext_vector_type(8))) short bf16x8;
typedef __attribute__((ext_vector_type(4))) float f32x4;
typedef __attribute__((ext_vector_type(4))) short short4v;

// ws layout (bytes):
//   [0, 524288)          hr bf16      1024*256*2
//   [524288, 528384)     hr_sq f32    1024
//   [528384, 928384)     ent_sq f32   100000
//   [928384, 936576)     packed u64   1024
//   [1048576, +51.2MB)   ent bf16     100000*256*2   (only if ws_size allows)
#define WS_HRSQ   524288
#define WS_ENTSQ  528384
#define WS_PACKED 928384
#define WS_ENTB   1048576
#define WS_NEED   (WS_ENTB + (size_t)NE * KD * 2)

#define AS1 __attribute__((address_space(1)))
#define AS3 __attribute__((address_space(3)))

__device__ __forceinline__ void gld_lds16(const void* g, void* l) {
    __builtin_amdgcn_global_load_lds((const AS1 unsigned int*)g,
                                     (AS3 unsigned int*)l, 16, 0, 0);
}

__device__ __forceinline__ unsigned short f2bf(float f) {
    union { float f; unsigned int u; } v; v.f = f;
    unsigned int u = v.u;
    return (unsigned short)((u + 0x7FFFu + ((u >> 16) & 1u)) >> 16);
}

__device__ __forceinline__ bf16x8 pack8(float4 a, float4 b) {
    bf16x8 t;
    t[0] = (short)f2bf(a.x); t[1] = (short)f2bf(a.y);
    t[2] = (short)f2bf(a.z); t[3] = (short)f2bf(a.w);
    t[4] = (short)f2bf(b.x); t[5] = (short)f2bf(b.y);
    t[6] = (short)f2bf(b.z); t[7] = (short)f2bf(b.w);
    return t;
}

// ---- prep: hr = E[head] + R[rel] -> bf16; hr_sq; init packed argmax ----
__global__ __launch_bounds__(64) void prep_kernel(const int* __restrict__ q,
                                                  const float* __restrict__ ent,
                                                  const float* __restrict__ rel,
                                                  unsigned short* __restrict__ hrb,
                                                  float* __restrict__ hrsq,
                                                  unsigned long long* __restrict__ packed) {
    int b = blockIdx.x;
    int lane = threadIdx.x;
    int head = q[b * 3 + 0];
    int r    = q[b * 3 + 1];
    float4 e  = ((const float4*)(ent + (size_t)head * KD))[lane];
    float4 rv = ((const float4*)(rel + (size_t)r * KD))[lane];
    float4 h; h.x = e.x + rv.x; h.y = e.y + rv.y; h.z = e.z + rv.z; h.w = e.w + rv.w;
    short4v hv;
    hv[0] = (short)f2bf(h.x); hv[1] = (short)f2bf(h.y);
    hv[2] = (short)f2bf(h.z); hv[3] = (short)f2bf(h.w);
    *(short4v*)(hrb + (size_t)b * KD + lane * 4) = hv;
    float sq = h.x * h.x + h.y * h.y + h.z * h.z + h.w * h.w;
    #pragma unroll
    for (int off = 32; off > 0; off >>= 1) sq += __shfl_down(sq, off, 64);
    if (lane == 0) { hrsq[b] = sq; packed[b] = 0ull; }
}

// ---- fused: ent f32 -> bf16 + ent_sq. Half-wave per row ----
__global__ __launch_bounds__(256) void conv_entsq_kernel(const float* __restrict__ ent,
                                                         unsigned short* __restrict__ entb,
                                                         float* __restrict__ entsq) {
    int gw   = (blockIdx.x * 256 + threadIdx.x) >> 6;
    int lane = threadIdx.x & 63;
    int row  = gw * 2 + (lane >> 5);
    if (row >= NE) return;
    const float4* src = (const float4*)(ent + (size_t)row * KD) + (lane & 31) * 2;
    float4 a = src[0], b = src[1];
    *(bf16x8*)(entb + (size_t)row * KD + (lane & 31) * 8) = pack8(a, b);
    float s = a.x * a.x + a.y * a.y + a.z * a.z + a.w * a.w
            + b.x * b.x + b.y * b.y + b.z * b.z + b.w * b.w;
    #pragma unroll
    for (int off = 16; off > 0; off >>= 1) s += __shfl_xor(s, off, 64);
    if ((lane & 31) == 0) entsq[row] = s;
}

// ---- ent_sq only (fallback path) ----
__global__ __launch_bounds__(256) void entsq_kernel(const float* __restrict__ ent,
                                                    float* __restrict__ entsq) {
    int w = threadIdx.x >> 6, lane = threadIdx.x & 63;
    int n = blockIdx.x * 4 + w;
    if (n >= NE) return;
    float4 v = ((const float4*)(ent + (size_t)n * KD))[lane];
    float s = v.x * v.x + v.y * v.y + v.z * v.z + v.w * v.w;
    #pragma unroll
    for (int off = 32; off > 0; off >>= 1) s += __shfl_down(s, off, 64);
    if (lane == 0) entsq[n] = s;
}

// ---- GEMM v3: one-shot LDS-staged B (full K), A hoisted to regs, no K-loop
//      barriers; swizzled LDS; fused epilogue + argmax; nontemporal stores ----
__global__ __launch_bounds__(256, 2) void gemm_v3(const unsigned short* __restrict__ hrb,
                                                  const unsigned short* __restrict__ entb,
                                                  const float* __restrict__ hrsq,
                                                  const float* __restrict__ entsq,
                                                  float* __restrict__ out,
                                                  unsigned long long* __restrict__ packed) {
    __shared__ __align__(16) char Bs[128 * 512];   // 64 KB, swizzled bf16 tile

    const int bid  = blockIdx.x;
    const int wgid = (bid & 7) * NT + (bid >> 3);  // XCD-chunked swizzle
    const int mt = wgid & 7, nt = wgid >> 3;
    const int m0 = mt * 128, n0 = nt * 128;

    const int tid  = threadIdx.x;
    const int lane = tid & 63;
    const int wid  = tid >> 6;
    const int wr = wid >> 1, wc = wid & 1;
    const int lr = lane & 15;
    const int lk = (lane >> 4) * 8;   // k elem offset of fragment slice

    // ---- stage B tile: 16 x global_load_lds(16B) per thread-slot, swizzled.
    // LDS[L] = tile[G], G = L ^ ((row&7)<<4); row bits (>=9) unchanged by XOR.
    {
        const char* eb = (const char*)entb;
        #pragma unroll
        for (int i = 0; i < 16; ++i) {
            int L = i * 4096 + wid * 1024 + lane * 16;
            int G = L ^ (((L >> 9) & 7) << 4);
            int row = n0 + (L >> 9);
            row = row < NE ? row : (NE - 1);
            const void* src = eb + (size_t)row * 512 + (G & 511);
            void* dst = Bs + i * 4096 + wid * 1024;   // wave-uniform base
            gld_lds16(src, dst);
        }
    }

    // ---- hoist ALL A fragments (32 x 16B loads, 128 VGPR) ----
    const unsigned short* aP[4];
    #pragma unroll
    for (int i = 0; i < 4; ++i) {
        int ar = m0 + wr * 64 + i * 16 + lr;
        aP[i] = hrb + (size_t)ar * KD + lk;
    }
    bf16x8 af[8][4];
    #pragma unroll
    for (int ks = 0; ks < 8; ++ks)
        #pragma unroll
        for (int i = 0; i < 4; ++i)
            af[ks][i] = *(const bf16x8*)(aP[i] + ks * 32);

    f32x4 acc[4][4];
    #pragma unroll
    for (int m = 0; m < 4; ++m)
        #pragma unroll
        for (int n = 0; n < 4; ++n)
            acc[m][n] = (f32x4){0.f, 0.f, 0.f, 0.f};

    __syncthreads();   // drains staging + A loads (vmcnt(0))

    // ---- compute: pure LDS + MFMA, no barriers ----
    #pragma unroll
    for (int ks = 0; ks < 8; ++ks) {
        bf16x8 bfr[4];
        #pragma unroll
        for (int n = 0; n < 4; ++n) {
            int r  = wc * 64 + n * 16 + lr;
            int kb = ks * 64 + ((lane >> 4) << 4);
            int byte = r * 512 + (kb ^ ((r & 7) << 4));
            bfr[n] = *(const bf16x8*)((const char*)Bs + byte);
        }
        #pragma unroll
        for (int m = 0; m < 4; ++m)
            #pragma unroll
            for (int n = 0; n < 4; ++n)
                acc[m][n] = __builtin_amdgcn_mfma_f32_16x16x32_bf16(af[ks][m], bfr[n], acc[m][n], 0, 0, 0);
    }

    // ---- epilogue: scores = 2*cross - hr_sq - ent_sq, fused argmax ----
    int   cg[4];
    bool  cv[4];
    float eq[4];
    #pragma unroll
    for (int n = 0; n < 4; ++n) {
        cg[n] = n0 + wc * 64 + n * 16 + lr;
        cv[n] = cg[n] < NE;
        eq[n] = cv[n] ? entsq[cg[n]] : 0.f;
    }

    #pragma unroll
    for (int m = 0; m < 4; ++m) {
        #pragma unroll
        for (int j = 0; j < 4; ++j) {
            int rg = m0 + wr * 64 + m * 16 + ((lane >> 4) << 2) + j;
            float hq = hrsq[rg];
            size_t ro = (size_t)rg * NE;
            unsigned long long best = 0ull;
            #pragma unroll
            for (int n = 0; n < 4; ++n) {
                if (cv[n]) {
                    float s = 2.0f * acc[m][n][j] - hq - eq[n];
                    __builtin_nontemporal_store(s, &out[ro + cg[n]]);
                    unsigned int u = __float_as_uint(s);
                    unsigned int key = u ^ ((unsigned int)((int)u >> 31) | 0x80000000u);
                    unsigned long long k64 =
                        ((unsigned long long)key << 32) | (unsigned int)(~cg[n]);
                    best = (k64 > best) ? k64 : best;
                }
            }
            #pragma unroll
            for (int off = 8; off > 0; off >>= 1) {
                unsigned long long o =
                    (unsigned long long)__shfl_xor((long long)best, off, 16);
                best = (o > best) ? o : best;
            }
            if (lr == 0) atomicMax(packed + rg, best);
        }
    }
}

// ---- fallback GEMM (B from f32 directly), from R2 ----
__global__ __launch_bounds__(256, 3) void gemm_direct_f32(const unsigned short* __restrict__ hrb,
                                                          const float* __restrict__ entf,
                                                          const float* __restrict__ hrsq,
                                                          const float* __restrict__ entsq,
                                                          float* __restrict__ out,
                                                          unsigned long long* __restrict__ packed) {
    const int bid  = blockIdx.x;
    const int wgid = (bid & 7) * NT + (bid >> 3);
    const int mt = wgid & 7, nt = wgid >> 3;
    const int m0 = mt * 128, n0 = nt * 128;
    const int tid  = threadIdx.x;
    const int lane = tid & 63;
    const int wid  = tid >> 6;
    const int wr = wid >> 1, wc = wid & 1;
    const int lr = lane & 15;
    const int lk = (lane >> 4) * 8;

    const unsigned short* aP[4];
    const float*          bPf[4];
    int  cg[4];
    bool cv[4];
    #pragma unroll
    for (int i = 0; i < 4; ++i) {
        int ar = m0 + wr * 64 + i * 16 + lr;
        aP[i] = hrb + (size_t)ar * KD + lk;
        int nr = n0 + wc * 64 + i * 16 + lr;
        cg[i] = nr; cv[i] = nr < NE;
        bPf[i] = entf + (size_t)(cv[i] ? nr : 0) * KD + lk;
    }

    f32x4 acc[4][4];
    #pragma unroll
    for (int m = 0; m < 4; ++m)
        #pragma unroll
        for (int n = 0; n < 4; ++n)
            acc[m][n] = (f32x4){0.f, 0.f, 0.f, 0.f};

    #pragma unroll
    for (int ks = 0; ks < KD / 32; ++ks) {
        bf16x8 af[4], bfr[4];
        #pragma unroll
        for (int i = 0; i < 4; ++i)
            af[i] = *(const bf16x8*)(aP[i] + ks * 32);
        #pragma unroll
        for (int i = 0; i < 4; ++i) {
            const float4* p = (const float4*)(bPf[i] + ks * 32);
            bfr[i] = pack8(p[0], p[1]);
        }
        #pragma unroll
        for (int m = 0; m < 4; ++m)
            #pragma unroll
            for (int n = 0; n < 4; ++n)
                acc[m][n] = __builtin_amdgcn_mfma_f32_16x16x32_bf16(af[m], bfr[n], acc[m][n], 0, 0, 0);
    }

    float eq[4];
    #pragma unroll
    for (int n = 0; n < 4; ++n) eq[n] = cv[n] ? entsq[cg[n]] : 0.f;
    #pragma unroll
    for (int m = 0; m < 4; ++m) {
        #pragma unroll
        for (int j = 0; j < 4; ++j) {
            int rg = m0 + wr * 64 + m * 16 + ((lane >> 4) << 2) + j;
            float hq = hrsq[rg];
            size_t ro = (size_t)rg * NE;
            unsigned long long best = 0ull;
            #pragma unroll
            for (int n = 0; n < 4; ++n) {
                if (cv[n]) {
                    float s = 2.0f * acc[m][n][j] - hq - eq[n];
                    out[ro + cg[n]] = s;
                    unsigned int u = __float_as_uint(s);
                    unsigned int key = u ^ ((unsigned int)((int)u >> 31) | 0x80000000u);
                    unsigned long long k64 =
                        ((unsigned long long)key << 32) | (unsigned int)(~cg[n]);
                    best = (k64 > best) ? k64 : best;
                }
            }
            #pragma unroll
            for (int off = 8; off > 0; off >>= 1) {
                unsigned long long o =
                    (unsigned long long)__shfl_xor((long long)best, off, 16);
                best = (o > best) ? o : best;
            }
            if (lr == 0) atomicMax(packed + rg, best);
        }
    }
}

// ---- finalize: unpack argmax col, store as float ----
__global__ __launch_bounds__(256) void final_kernel(const unsigned long long* __restrict__ packed,
                                                    float* __restrict__ pred) {
    int b = blockIdx.x * 256 + threadIdx.x;
    if (b < MM) {
        unsigned int ic = (unsigned int)(packed[b] & 0xFFFFFFFFull);
        pred[b] = (float)(~ic);
    }
}

extern "C" void kernel_launch(void* const* d_in, const int* in_sizes, int n_in,
                              void* d_out, int out_size, void* d_ws, size_t ws_size,
                              hipStream_t stream) {
    const int*   q   = (const int*)d_in[0];
    const float* ent = (const float*)d_in[1];
    const float* rel = (const float*)d_in[2];
    float* out = (float*)d_out;
    char*  ws  = (char*)d_ws;

    unsigned short*     hrb    = (unsigned short*)ws;
    float*              hrsq   = (float*)(ws + WS_HRSQ);
    float*              entsq  = (float*)(ws + WS_ENTSQ);
    unsigned long long* packed = (unsigned long long*)(ws + WS_PACKED);
    unsigned short*     entb   = (unsigned short*)(ws + WS_ENTB);
    float* pred = out + (size_t)MM * NE;

    prep_kernel<<<MM, 64, 0, stream>>>(q, ent, rel, hrb, hrsq, packed);

    if (ws_size >= WS_NEED) {
        conv_entsq_kernel<<<12500, 256, 0, stream>>>(ent, entb, entsq);
        gemm_v3<<<MT * NT, 256, 0, stream>>>(hrb, entb, hrsq, entsq, out, packed);
    } else {
        entsq_kernel<<<(NE + 3) / 4, 256, 0, stream>>>(ent, entsq);
        gemm_direct_f32<<<MT * NT, 256, 0, stream>>>(hrb, ent, hrsq, entsq, out, packed);
    }

    final_kernel<<<(MM + 255) / 256, 256, 0, stream>>>(packed, pred);
}

// Round 4
// 323.479 us; speedup vs baseline: 2.1500x; 1.1126x over previous
//
#include <hip/hip_runtime.h>

#define MM 1024
#define NE 100000
#define KD 256
#define NT 782   // ceil(NE/128)
#define MT 8     // 1024/128
#define PSTRIDE 784

typedef __attribute__((ext_vector_type(8))) short bf16x8;
typedef __attribute__((ext_vector_type(4))) float f32x4;
typedef __attribute__((ext_vector_type(4))) short short4v;

// ws layout (bytes):
//   [0, 524288)            hr bf16      1024*256*2
//   [524288, 528384)       hr_sq f32    1024
//   [528384, 928384)       ent_sq f32   100000
//   [1048576, 7471104)     argmax partials u64 [1024][784] (only [.][0..781] written)
//   [8388608, +51.2MB)     ent bf16     100000*256*2   (tier A only)
#define WS_HRSQ   524288
#define WS_ENTSQ  528384
#define WS_PART   1048576
#define WS_ENTB   8388608
#define WS_NEED   (WS_ENTB + (size_t)NE * KD * 2)

#define AS1 __attribute__((address_space(1)))
#define AS3 __attribute__((address_space(3)))

__device__ __forceinline__ void gld_lds16(const void* g, void* l) {
    __builtin_amdgcn_global_load_lds((const AS1 unsigned int*)g,
                                     (AS3 unsigned int*)l, 16, 0, 0);
}

__device__ __forceinline__ unsigned short f2bf(float f) {
    union { float f; unsigned int u; } v; v.f = f;
    unsigned int u = v.u;
    return (unsigned short)((u + 0x7FFFu + ((u >> 16) & 1u)) >> 16);
}

__device__ __forceinline__ bf16x8 pack8(float4 a, float4 b) {
    bf16x8 t;
    t[0] = (short)f2bf(a.x); t[1] = (short)f2bf(a.y);
    t[2] = (short)f2bf(a.z); t[3] = (short)f2bf(a.w);
    t[4] = (short)f2bf(b.x); t[5] = (short)f2bf(b.y);
    t[6] = (short)f2bf(b.z); t[7] = (short)f2bf(b.w);
    return t;
}

// monotonic pack: bigger score -> bigger key; ties -> smaller col wins
__device__ __forceinline__ unsigned long long packkey(float s, int col) {
    unsigned int u = __float_as_uint(s);
    unsigned int key = u ^ ((unsigned int)((int)u >> 31) | 0x80000000u);
    return ((unsigned long long)key << 32) | (unsigned int)(~col);
}

// ---- prep: hr = E[head] + R[rel] -> bf16; hr_sq ----
__global__ __launch_bounds__(64) void prep_kernel(const int* __restrict__ q,
                                                  const float* __restrict__ ent,
                                                  const float* __restrict__ rel,
                                                  unsigned short* __restrict__ hrb,
                                                  float* __restrict__ hrsq) {
    int b = blockIdx.x;
    int lane = threadIdx.x;
    int head = q[b * 3 + 0];
    int r    = q[b * 3 + 1];
    float4 e  = ((const float4*)(ent + (size_t)head * KD))[lane];
    float4 rv = ((const float4*)(rel + (size_t)r * KD))[lane];
    float4 h; h.x = e.x + rv.x; h.y = e.y + rv.y; h.z = e.z + rv.z; h.w = e.w + rv.w;
    short4v hv;
    hv[0] = (short)f2bf(h.x); hv[1] = (short)f2bf(h.y);
    hv[2] = (short)f2bf(h.z); hv[3] = (short)f2bf(h.w);
    *(short4v*)(hrb + (size_t)b * KD + lane * 4) = hv;
    float sq = h.x * h.x + h.y * h.y + h.z * h.z + h.w * h.w;
    #pragma unroll
    for (int off = 32; off > 0; off >>= 1) sq += __shfl_down(sq, off, 64);
    if (lane == 0) hrsq[b] = sq;
}

// ---- fused: ent f32 -> bf16 + ent_sq ----
__global__ __launch_bounds__(256) void conv_entsq_kernel(const float* __restrict__ ent,
                                                         unsigned short* __restrict__ entb,
                                                         float* __restrict__ entsq) {
    int gw   = (blockIdx.x * 256 + threadIdx.x) >> 6;
    int lane = threadIdx.x & 63;
    int row  = gw * 2 + (lane >> 5);
    if (row >= NE) return;
    const float4* src = (const float4*)(ent + (size_t)row * KD) + (lane & 31) * 2;
    float4 a = src[0], b = src[1];
    *(bf16x8*)(entb + (size_t)row * KD + (lane & 31) * 8) = pack8(a, b);
    float s = a.x * a.x + a.y * a.y + a.z * a.z + a.w * a.w
            + b.x * b.x + b.y * b.y + b.z * b.z + b.w * b.w;
    #pragma unroll
    for (int off = 16; off > 0; off >>= 1) s += __shfl_xor(s, off, 64);
    if ((lane & 31) == 0) entsq[row] = s;
}

// ---- ent_sq only (fallback path) ----
__global__ __launch_bounds__(256) void entsq_kernel(const float* __restrict__ ent,
                                                    float* __restrict__ entsq) {
    int w = threadIdx.x >> 6, lane = threadIdx.x & 63;
    int n = blockIdx.x * 4 + w;
    if (n >= NE) return;
    float4 v = ((const float4*)(ent + (size_t)n * KD))[lane];
    float s = v.x * v.x + v.y * v.y + v.z * v.z + v.w * v.w;
    #pragma unroll
    for (int off = 32; off > 0; off >>= 1) s += __shfl_down(s, off, 64);
    if (lane == 0) entsq[n] = s;
}

// ---- GEMM v4: one-shot LDS B, A hoisted; atomic-free argmax partials ----
__global__ __launch_bounds__(256, 2) void gemm_v4(const unsigned short* __restrict__ hrb,
                                                  const unsigned short* __restrict__ entb,
                                                  const float* __restrict__ hrsq,
                                                  const float* __restrict__ entsq,
                                                  float* __restrict__ out,
                                                  unsigned long long* __restrict__ part) {
    __shared__ __align__(16) char Bs[128 * 512];          // 64 KB swizzled bf16 tile
    __shared__ unsigned long long lds_best[2][128];       // per-wc per-row partial

    const int bid  = blockIdx.x;
    const int wgid = (bid & 7) * NT + (bid >> 3);         // XCD-chunked swizzle
    const int mt = wgid & 7, nt = wgid >> 3;
    const int m0 = mt * 128, n0 = nt * 128;

    const int tid  = threadIdx.x;
    const int lane = tid & 63;
    const int wid  = tid >> 6;
    const int wr = wid >> 1, wc = wid & 1;
    const int lr = lane & 15;
    const int lk = (lane >> 4) * 8;

    // ---- stage B tile (swizzled source -> linear LDS dest) ----
    {
        const char* eb = (const char*)entb;
        #pragma unroll
        for (int i = 0; i < 16; ++i) {
            int L = i * 4096 + wid * 1024 + lane * 16;
            int G = L ^ (((L >> 9) & 7) << 4);
            int row = n0 + (L >> 9);
            row = row < NE ? row : (NE - 1);
            const void* src = eb + (size_t)row * 512 + (G & 511);
            void* dst = Bs + i * 4096 + wid * 1024;
            gld_lds16(src, dst);
        }
    }

    // ---- column indices + entsq (hoisted, hides latency under staging) ----
    int   cg[4];
    bool  cv[4];
    float eq[4];
    #pragma unroll
    for (int n = 0; n < 4; ++n) {
        cg[n] = n0 + wc * 64 + n * 16 + lr;
        cv[n] = cg[n] < NE;
        eq[n] = cv[n] ? entsq[cv[n] ? cg[n] : 0] : 0.f;
    }

    // ---- hoist A fragments ----
    const unsigned short* aP[4];
    #pragma unroll
    for (int i = 0; i < 4; ++i) {
        int ar = m0 + wr * 64 + i * 16 + lr;
        aP[i] = hrb + (size_t)ar * KD + lk;
    }
    bf16x8 af[8][4];
    #pragma unroll
    for (int ks = 0; ks < 8; ++ks)
        #pragma unroll
        for (int i = 0; i < 4; ++i)
            af[ks][i] = *(const bf16x8*)(aP[i] + ks * 32);

    f32x4 acc[4][4];
    #pragma unroll
    for (int m = 0; m < 4; ++m)
        #pragma unroll
        for (int n = 0; n < 4; ++n)
            acc[m][n] = (f32x4){0.f, 0.f, 0.f, 0.f};

    __syncthreads();   // drains staging (vmcnt(0))

    // ---- compute: pure LDS + MFMA ----
    #pragma unroll
    for (int ks = 0; ks < 8; ++ks) {
        bf16x8 bfr[4];
        #pragma unroll
        for (int n = 0; n < 4; ++n) {
            int r  = wc * 64 + n * 16 + lr;
            int kb = ks * 64 + ((lane >> 4) << 4);
            int byte = r * 512 + (kb ^ ((r & 7) << 4));
            bfr[n] = *(const bf16x8*)((const char*)Bs + byte);
        }
        #pragma unroll
        for (int m = 0; m < 4; ++m)
            #pragma unroll
            for (int n = 0; n < 4; ++n)
                acc[m][n] = __builtin_amdgcn_mfma_f32_16x16x32_bf16(af[ks][m], bfr[n], acc[m][n], 0, 0, 0);
    }

    // ---- epilogue: scores + per-row argmax partial (no atomics) ----
    // wave covers 64 rows: rl64 = wr*64 + m*16 + g*4 + j  (g = lane>>4)
    unsigned long long rowbest[4][4];   // [m][j] best over this thread's 4 cols
    #pragma unroll
    for (int m = 0; m < 4; ++m) {
        #pragma unroll
        for (int j = 0; j < 4; ++j) {
            int rg = m0 + wr * 64 + m * 16 + ((lane >> 4) << 2) + j;
            float hq = hrsq[rg];
            size_t ro = (size_t)rg * NE;
            unsigned long long best = 0ull;
            #pragma unroll
            for (int n = 0; n < 4; ++n) {
                if (cv[n]) {
                    float s = 2.0f * acc[m][n][j] - hq - eq[n];
                    out[ro + cg[n]] = s;
                    unsigned long long k64 = packkey(s, cg[n]);
                    best = (k64 > best) ? k64 : best;
                }
            }
            // reduce over the 16 lanes of this row-group
            #pragma unroll
            for (int off = 8; off > 0; off >>= 1) {
                unsigned long long o =
                    (unsigned long long)__shfl_xor((long long)best, off, 16);
                best = (o > best) ? o : best;
            }
            rowbest[m][j] = best;
        }
    }
    // lr==0 lanes deposit: row index within block = wr*64 + m*16 + g*4 + j
    if (lr == 0) {
        int g = lane >> 4;
        #pragma unroll
        for (int m = 0; m < 4; ++m)
            #pragma unroll
            for (int j = 0; j < 4; ++j)
                lds_best[wc][wr * 64 + m * 16 + g * 4 + j] = rowbest[m][j];
    }
    __syncthreads();
    // first 128 threads: combine the two column-halves, one store per row
    if (tid < 128) {
        unsigned long long a = lds_best[0][tid];
        unsigned long long b = lds_best[1][tid];
        unsigned long long best = a > b ? a : b;
        part[(size_t)(m0 + tid) * PSTRIDE + nt] = best;
    }
}

// ---- fallback GEMM (B from f32 directly), atomic-free partials ----
__global__ __launch_bounds__(256, 3) void gemm_direct_f32(const unsigned short* __restrict__ hrb,
                                                          const float* __restrict__ entf,
                                                          const float* __restrict__ hrsq,
                                                          const float* __restrict__ entsq,
                                                          float* __restrict__ out,
                                                          unsigned long long* __restrict__ part) {
    __shared__ unsigned long long lds_best[2][128];
    const int bid  = blockIdx.x;
    const int wgid = (bid & 7) * NT + (bid >> 3);
    const int mt = wgid & 7, nt = wgid >> 3;
    const int m0 = mt * 128, n0 = nt * 128;
    const int tid  = threadIdx.x;
    const int lane = tid & 63;
    const int wid  = tid >> 6;
    const int wr = wid >> 1, wc = wid & 1;
    const int lr = lane & 15;
    const int lk = (lane >> 4) * 8;

    const unsigned short* aP[4];
    const float*          bPf[4];
    int  cg[4];
    bool cv[4];
    #pragma unroll
    for (int i = 0; i < 4; ++i) {
        int ar = m0 + wr * 64 + i * 16 + lr;
        aP[i] = hrb + (size_t)ar * KD + lk;
        int nr = n0 + wc * 64 + i * 16 + lr;
        cg[i] = nr; cv[i] = nr < NE;
        bPf[i] = entf + (size_t)(cv[i] ? nr : 0) * KD + lk;
    }

    f32x4 acc[4][4];
    #pragma unroll
    for (int m = 0; m < 4; ++m)
        #pragma unroll
        for (int n = 0; n < 4; ++n)
            acc[m][n] = (f32x4){0.f, 0.f, 0.f, 0.f};

    #pragma unroll
    for (int ks = 0; ks < KD / 32; ++ks) {
        bf16x8 af[4], bfr[4];
        #pragma unroll
        for (int i = 0; i < 4; ++i)
            af[i] = *(const bf16x8*)(aP[i] + ks * 32);
        #pragma unroll
        for (int i = 0; i < 4; ++i) {
            const float4* p = (const float4*)(bPf[i] + ks * 32);
            bfr[i] = pack8(p[0], p[1]);
        }
        #pragma unroll
        for (int m = 0; m < 4; ++m)
            #pragma unroll
            for (int n = 0; n < 4; ++n)
                acc[m][n] = __builtin_amdgcn_mfma_f32_16x16x32_bf16(af[m], bfr[n], acc[m][n], 0, 0, 0);
    }

    float eq[4];
    #pragma unroll
    for (int n = 0; n < 4; ++n) eq[n] = cv[n] ? entsq[cg[n]] : 0.f;

    unsigned long long rowbest[4][4];
    #pragma unroll
    for (int m = 0; m < 4; ++m) {
        #pragma unroll
        for (int j = 0; j < 4; ++j) {
            int rg = m0 + wr * 64 + m * 16 + ((lane >> 4) << 2) + j;
            float hq = hrsq[rg];
            size_t ro = (size_t)rg * NE;
            unsigned long long best = 0ull;
            #pragma unroll
            for (int n = 0; n < 4; ++n) {
                if (cv[n]) {
                    float s = 2.0f * acc[m][n][j] - hq - eq[n];
                    out[ro + cg[n]] = s;
                    unsigned long long k64 = packkey(s, cg[n]);
                    best = (k64 > best) ? k64 : best;
                }
            }
            #pragma unroll
            for (int off = 8; off > 0; off >>= 1) {
                unsigned long long o =
                    (unsigned long long)__shfl_xor((long long)best, off, 16);
                best = (o > best) ? o : best;
            }
            rowbest[m][j] = best;
        }
    }
    if (lr == 0) {
        int g = lane >> 4;
        #pragma unroll
        for (int m = 0; m < 4; ++m)
            #pragma unroll
            for (int j = 0; j < 4; ++j)
                lds_best[wc][wr * 64 + m * 16 + g * 4 + j] = rowbest[m][j];
    }
    __syncthreads();
    if (tid < 128) {
        unsigned long long a = lds_best[0][tid];
        unsigned long long b = lds_best[1][tid];
        unsigned long long best = a > b ? a : b;
        part[(size_t)(m0 + tid) * PSTRIDE + nt] = best;
    }
}

// ---- reduce: per row, max over 782 partials -> prediction ----
__global__ __launch_bounds__(256) void reduce_kernel(const unsigned long long* __restrict__ part,
                                                     float* __restrict__ pred) {
    __shared__ unsigned long long sb[256];
    int row = blockIdx.x;
    int tid = threadIdx.x;
    const unsigned long long* base = part + (size_t)row * PSTRIDE;
    unsigned long long best = 0ull;
    for (int i = tid; i < NT; i += 256) {
        unsigned long long v = base[i];
        best = v > best ? v : best;
    }
    sb[tid] = best;
    __syncthreads();
    #pragma unroll
    for (int s = 128; s > 0; s >>= 1) {
        if (tid < s) {
            unsigned long long o = sb[tid + s];
            if (o > sb[tid]) sb[tid] = o;
        }
        __syncthreads();
    }
    if (tid == 0) {
        unsigned int ic = (unsigned int)(sb[0] & 0xFFFFFFFFull);
        pred[row] = (float)(~ic);
    }
}

extern "C" void kernel_launch(void* const* d_in, const int* in_sizes, int n_in,
                              void* d_out, int out_size, void* d_ws, size_t ws_size,
                              hipStream_t stream) {
    const int*   q   = (const int*)d_in[0];
    const float* ent = (const float*)d_in[1];
    const float* rel = (const float*)d_in[2];
    float* out = (float*)d_out;
    char*  ws  = (char*)d_ws;

    unsigned short*     hrb   = (unsigned short*)ws;
    float*              hrsq  = (float*)(ws + WS_HRSQ);
    float*              entsq = (float*)(ws + WS_ENTSQ);
    unsigned long long* part  = (unsigned long long*)(ws + WS_PART);
    unsigned short*     entb  = (unsigned short*)(ws + WS_ENTB);
    float* pred = out + (size_t)MM * NE;

    prep_kernel<<<MM, 64, 0, stream>>>(q, ent, rel, hrb, hrsq);

    if (ws_size >= WS_NEED) {
        conv_entsq_kernel<<<12500, 256, 0, stream>>>(ent, entb, entsq);
        gemm_v4<<<MT * NT, 256, 0, stream>>>(hrb, entb, hrsq, entsq, out, part);
    } else {
        entsq_kernel<<<(NE + 3) / 4, 256, 0, stream>>>(ent, entsq);
        gemm_direct_f32<<<MT * NT, 256, 0, stream>>>(hrb, ent, hrsq, entsq, out, part);
    }

    reduce_kernel<<<MM, 256, 0, stream>>>(part, pred);
}

// Round 5
// 271.731 us; speedup vs baseline: 2.5595x; 1.1904x over previous
//
#include <hip/hip_runtime.h>

#define MM 1024
#define NE 100000
#define KD 256
#define NT 782      // ceil(NE/128)
#define NGRP 64     // n-tile groups (persistent)
#define PSTRIDE 784

typedef __attribute__((ext_vector_type(8))) short bf16x8;
typedef __attribute__((ext_vector_type(4))) float f32x4;
typedef __attribute__((ext_vector_type(4))) short short4v;

// ws layout (bytes):
//   [0, 524288)            hr bf16      1024*256*2
//   [524288, 528384)       hr_sq f32    1024
//   [528384, 928384)       ent_sq f32   100000
//   [1048576, 7471104)     argmax partials u64 [1024][784]
//   [8388608, +51.2MB)     ent bf16     100000*256*2   (tier A only)
#define WS_HRSQ   524288
#define WS_ENTSQ  528384
#define WS_PART   1048576
#define WS_ENTB   8388608
#define WS_NEED   (WS_ENTB + (size_t)NE * KD * 2)

#define AS1 __attribute__((address_space(1)))
#define AS3 __attribute__((address_space(3)))

__device__ __forceinline__ void gld_lds16(const void* g, void* l) {
    __builtin_amdgcn_global_load_lds((const AS1 unsigned int*)g,
                                     (AS3 unsigned int*)l, 16, 0, 0);
}

__device__ __forceinline__ unsigned short f2bf(float f) {
    union { float f; unsigned int u; } v; v.f = f;
    unsigned int u = v.u;
    return (unsigned short)((u + 0x7FFFu + ((u >> 16) & 1u)) >> 16);
}

__device__ __forceinline__ bf16x8 pack8(float4 a, float4 b) {
    bf16x8 t;
    t[0] = (short)f2bf(a.x); t[1] = (short)f2bf(a.y);
    t[2] = (short)f2bf(a.z); t[3] = (short)f2bf(a.w);
    t[4] = (short)f2bf(b.x); t[5] = (short)f2bf(b.y);
    t[6] = (short)f2bf(b.z); t[7] = (short)f2bf(b.w);
    return t;
}

// monotonic pack: bigger score -> bigger key; ties -> smaller col wins
__device__ __forceinline__ unsigned long long packkey(float s, int col) {
    unsigned int u = __float_as_uint(s);
    unsigned int key = u ^ ((unsigned int)((int)u >> 31) | 0x80000000u);
    return ((unsigned long long)key << 32) | (unsigned int)(~col);
}

// ---- prep: hr = E[head] + R[rel] -> bf16; hr_sq ----
__global__ __launch_bounds__(64) void prep_kernel(const int* __restrict__ q,
                                                  const float* __restrict__ ent,
                                                  const float* __restrict__ rel,
                                                  unsigned short* __restrict__ hrb,
                                                  float* __restrict__ hrsq) {
    int b = blockIdx.x;
    int lane = threadIdx.x;
    int head = q[b * 3 + 0];
    int r    = q[b * 3 + 1];
    float4 e  = ((const float4*)(ent + (size_t)head * KD))[lane];
    float4 rv = ((const float4*)(rel + (size_t)r * KD))[lane];
    float4 h; h.x = e.x + rv.x; h.y = e.y + rv.y; h.z = e.z + rv.z; h.w = e.w + rv.w;
    short4v hv;
    hv[0] = (short)f2bf(h.x); hv[1] = (short)f2bf(h.y);
    hv[2] = (short)f2bf(h.z); hv[3] = (short)f2bf(h.w);
    *(short4v*)(hrb + (size_t)b * KD + lane * 4) = hv;
    float sq = h.x * h.x + h.y * h.y + h.z * h.z + h.w * h.w;
    #pragma unroll
    for (int off = 32; off > 0; off >>= 1) sq += __shfl_down(sq, off, 64);
    if (lane == 0) hrsq[b] = sq;
}

// ---- fused: ent f32 -> bf16 + ent_sq ----
__global__ __launch_bounds__(256) void conv_entsq_kernel(const float* __restrict__ ent,
                                                         unsigned short* __restrict__ entb,
                                                         float* __restrict__ entsq) {
    int gw   = (blockIdx.x * 256 + threadIdx.x) >> 6;
    int lane = threadIdx.x & 63;
    int row  = gw * 2 + (lane >> 5);
    if (row >= NE) return;
    const float4* src = (const float4*)(ent + (size_t)row * KD) + (lane & 31) * 2;
    float4 a = src[0], b = src[1];
    *(bf16x8*)(entb + (size_t)row * KD + (lane & 31) * 8) = pack8(a, b);
    float s = a.x * a.x + a.y * a.y + a.z * a.z + a.w * a.w
            + b.x * b.x + b.y * b.y + b.z * b.z + b.w * b.w;
    #pragma unroll
    for (int off = 16; off > 0; off >>= 1) s += __shfl_xor(s, off, 64);
    if ((lane & 31) == 0) entsq[row] = s;
}

// ---- ent_sq only (fallback path) ----
__global__ __launch_bounds__(256) void entsq_kernel(const float* __restrict__ ent,
                                                    float* __restrict__ entsq) {
    int w = threadIdx.x >> 6, lane = threadIdx.x & 63;
    int n = blockIdx.x * 4 + w;
    if (n >= NE) return;
    float4 v = ((const float4*)(ent + (size_t)n * KD))[lane];
    float s = v.x * v.x + v.y * v.y + v.z * v.z + v.w * v.w;
    #pragma unroll
    for (int off = 32; off > 0; off >>= 1) s += __shfl_down(s, off, 64);
    if (lane == 0) entsq[n] = s;
}

// ---- GEMM v5: persistent blocks. A m-panel staged in LDS once; B streamed
//      fragment-direct; no barriers in n-loop; register argmax; one partial
//      store per row per block at the end. ----
__global__ __launch_bounds__(256, 2) void gemm_v5(const unsigned short* __restrict__ hrb,
                                                  const unsigned short* __restrict__ entb,
                                                  const float* __restrict__ hrsq,
                                                  const float* __restrict__ entsq,
                                                  float* __restrict__ out,
                                                  unsigned long long* __restrict__ part) {
    __shared__ __align__(16) char As[128 * 512];      // 64 KB swizzled bf16 A panel
    __shared__ unsigned long long lds_best[2][128];

    const int bid   = blockIdx.x;
    const int mtile = bid & 7;
    const int g     = bid >> 3;      // n-group: tiles g, g+64, ...
    const int m0    = mtile * 128;

    const int tid  = threadIdx.x;
    const int lane = tid & 63;
    const int wid  = tid >> 6;
    const int wr = wid >> 1, wc = wid & 1;
    const int lr = lane & 15;
    const int lg = lane >> 4;
    const int lk = lg * 8;           // k elem offset of fragment slice

    // ---- stage A panel (swizzled source -> linear LDS dest), once ----
    {
        const char* hb = (const char*)hrb;
        #pragma unroll
        for (int i = 0; i < 16; ++i) {
            int L = i * 4096 + wid * 1024 + lane * 16;
            int G = L ^ (((L >> 9) & 7) << 4);
            int row = m0 + (L >> 9);
            const void* src = hb + (size_t)row * 512 + (G & 511);
            void* dst = As + i * 4096 + wid * 1024;
            gld_lds16(src, dst);
        }
    }

    // ---- per-block row constants (hoisted out of the tile loop) ----
    unsigned rowIdx[4][4];
    float    hq[4][4];
    #pragma unroll
    for (int mm = 0; mm < 4; ++mm)
        #pragma unroll
        for (int j = 0; j < 4; ++j) {
            int rg = m0 + wr * 64 + mm * 16 + lg * 4 + j;
            rowIdx[mm][j] = (unsigned)rg * (unsigned)NE;
            hq[mm][j] = hrsq[rg];
        }

    float bestf[4][4];
    int   bestc[4][4];
    #pragma unroll
    for (int mm = 0; mm < 4; ++mm)
        #pragma unroll
        for (int j = 0; j < 4; ++j) { bestf[mm][j] = -3.4e38f; bestc[mm][j] = 0; }

    __syncthreads();   // A panel ready (drains staging)

    // ---- persistent n-tile loop: NO barriers inside ----
    for (int t = g; t < NT; t += NGRP) {
        const unsigned short* bP[4];
        int cg[4]; bool cv[4]; float eq[4];
        #pragma unroll
        for (int nn = 0; nn < 4; ++nn) {
            int nr = t * 128 + wc * 64 + nn * 16 + lr;
            cg[nn] = nr;
            cv[nn] = nr < NE;
            int nrc = cv[nn] ? nr : (NE - 1);
            bP[nn] = entb + (size_t)nrc * KD + lk;
            eq[nn] = entsq[nrc];
        }

        f32x4 acc[4][4];
        #pragma unroll
        for (int mm = 0; mm < 4; ++mm)
            #pragma unroll
            for (int nn = 0; nn < 4; ++nn)
                acc[mm][nn] = (f32x4){0.f, 0.f, 0.f, 0.f};

        #pragma unroll
        for (int ks = 0; ks < 8; ++ks) {
            bf16x8 bfr[4];
            #pragma unroll
            for (int nn = 0; nn < 4; ++nn)
                bfr[nn] = *(const bf16x8*)(bP[nn] + ks * 32);
            bf16x8 af[4];
            #pragma unroll
            for (int mm = 0; mm < 4; ++mm) {
                int r = wr * 64 + mm * 16 + lr;
                int byte = r * 512 + ((ks * 64 + lg * 16) ^ ((r & 7) << 4));
                af[mm] = *(const bf16x8*)((const char*)As + byte);
            }
            #pragma unroll
            for (int mm = 0; mm < 4; ++mm)
                #pragma unroll
                for (int nn = 0; nn < 4; ++nn)
                    acc[mm][nn] = __builtin_amdgcn_mfma_f32_16x16x32_bf16(af[mm], bfr[nn], acc[mm][nn], 0, 0, 0);
        }

        // epilogue: scores + in-register argmax (no shuffles, no barriers)
        #pragma unroll
        for (int mm = 0; mm < 4; ++mm) {
            #pragma unroll
            for (int j = 0; j < 4; ++j) {
                float hqe = hq[mm][j];
                unsigned ro = rowIdx[mm][j];
                #pragma unroll
                for (int nn = 0; nn < 4; ++nn) {
                    if (cv[nn]) {
                        float s = 2.0f * acc[mm][nn][j] - hqe - eq[nn];
                        out[ro + (unsigned)cg[nn]] = s;
                        if (s > bestf[mm][j]) { bestf[mm][j] = s; bestc[mm][j] = cg[nn]; }
                    }
                }
            }
        }
    }

    // ---- block-end argmax reduce: 16-lane shuffle, LDS combine, 1 store/row ----
    unsigned long long rowbest[4][4];
    #pragma unroll
    for (int mm = 0; mm < 4; ++mm)
        #pragma unroll
        for (int j = 0; j < 4; ++j) {
            unsigned long long best = packkey(bestf[mm][j], bestc[mm][j]);
            #pragma unroll
            for (int off = 8; off > 0; off >>= 1) {
                unsigned long long o =
                    (unsigned long long)__shfl_xor((long long)best, off, 16);
                best = (o > best) ? o : best;
            }
            rowbest[mm][j] = best;
        }
    if (lr == 0) {
        #pragma unroll
        for (int mm = 0; mm < 4; ++mm)
            #pragma unroll
            for (int j = 0; j < 4; ++j)
                lds_best[wc][wr * 64 + mm * 16 + lg * 4 + j] = rowbest[mm][j];
    }
    __syncthreads();
    if (tid < 128) {
        unsigned long long a = lds_best[0][tid];
        unsigned long long b = lds_best[1][tid];
        unsigned long long best = a > b ? a : b;
        part[(size_t)(m0 + tid) * PSTRIDE + g] = best;
    }
}

// ---- fallback GEMM (B from f32 directly), atomic-free partials ----
__global__ __launch_bounds__(256, 3) void gemm_direct_f32(const unsigned short* __restrict__ hrb,
                                                          const float* __restrict__ entf,
                                                          const float* __restrict__ hrsq,
                                                          const float* __restrict__ entsq,
                                                          float* __restrict__ out,
                                                          unsigned long long* __restrict__ part) {
    __shared__ unsigned long long lds_best[2][128];
    const int bid  = blockIdx.x;
    const int wgid = (bid & 7) * NT + (bid >> 3);
    const int mt = wgid & 7, nt = wgid >> 3;
    const int m0 = mt * 128, n0 = nt * 128;
    const int tid  = threadIdx.x;
    const int lane = tid & 63;
    const int wid  = tid >> 6;
    const int wr = wid >> 1, wc = wid & 1;
    const int lr = lane & 15;
    const int lk = (lane >> 4) * 8;

    const unsigned short* aP[4];
    const float*          bPf[4];
    int  cg[4];
    bool cv[4];
    #pragma unroll
    for (int i = 0; i < 4; ++i) {
        int ar = m0 + wr * 64 + i * 16 + lr;
        aP[i] = hrb + (size_t)ar * KD + lk;
        int nr = n0 + wc * 64 + i * 16 + lr;
        cg[i] = nr; cv[i] = nr < NE;
        bPf[i] = entf + (size_t)(cv[i] ? nr : 0) * KD + lk;
    }

    f32x4 acc[4][4];
    #pragma unroll
    for (int m = 0; m < 4; ++m)
        #pragma unroll
        for (int n = 0; n < 4; ++n)
            acc[m][n] = (f32x4){0.f, 0.f, 0.f, 0.f};

    #pragma unroll
    for (int ks = 0; ks < KD / 32; ++ks) {
        bf16x8 af[4], bfr[4];
        #pragma unroll
        for (int i = 0; i < 4; ++i)
            af[i] = *(const bf16x8*)(aP[i] + ks * 32);
        #pragma unroll
        for (int i = 0; i < 4; ++i) {
            const float4* p = (const float4*)(bPf[i] + ks * 32);
            bfr[i] = pack8(p[0], p[1]);
        }
        #pragma unroll
        for (int m = 0; m < 4; ++m)
            #pragma unroll
            for (int n = 0; n < 4; ++n)
                acc[m][n] = __builtin_amdgcn_mfma_f32_16x16x32_bf16(af[m], bfr[n], acc[m][n], 0, 0, 0);
    }

    float eq[4];
    #pragma unroll
    for (int n = 0; n < 4; ++n) eq[n] = cv[n] ? entsq[cg[n]] : 0.f;

    unsigned long long rowbest[4][4];
    #pragma unroll
    for (int m = 0; m < 4; ++m) {
        #pragma unroll
        for (int j = 0; j < 4; ++j) {
            int rg = m0 + wr * 64 + m * 16 + ((lane >> 4) << 2) + j;
            float hqv = hrsq[rg];
            size_t ro = (size_t)rg * NE;
            unsigned long long best = 0ull;
            #pragma unroll
            for (int n = 0; n < 4; ++n) {
                if (cv[n]) {
                    float s = 2.0f * acc[m][n][j] - hqv - eq[n];
                    out[ro + cg[n]] = s;
                    unsigned long long k64 = packkey(s, cg[n]);
                    best = (k64 > best) ? k64 : best;
                }
            }
            #pragma unroll
            for (int off = 8; off > 0; off >>= 1) {
                unsigned long long o =
                    (unsigned long long)__shfl_xor((long long)best, off, 16);
                best = (o > best) ? o : best;
            }
            rowbest[m][j] = best;
        }
    }
    if (lr == 0) {
        int gg = lane >> 4;
        #pragma unroll
        for (int m = 0; m < 4; ++m)
            #pragma unroll
            for (int j = 0; j < 4; ++j)
                lds_best[wc][wr * 64 + m * 16 + gg * 4 + j] = rowbest[m][j];
    }
    __syncthreads();
    if (tid < 128) {
        unsigned long long a = lds_best[0][tid];
        unsigned long long b = lds_best[1][tid];
        unsigned long long best = a > b ? a : b;
        part[(size_t)(m0 + tid) * PSTRIDE + nt] = best;
    }
}

// ---- reduce: per row, max over NP partials -> prediction ----
__global__ __launch_bounds__(256) void reduce_kernel(const unsigned long long* __restrict__ part,
                                                     float* __restrict__ pred, int np) {
    __shared__ unsigned long long sb[256];
    int row = blockIdx.x;
    int tid = threadIdx.x;
    const unsigned long long* base = part + (size_t)row * PSTRIDE;
    unsigned long long best = 0ull;
    for (int i = tid; i < np; i += 256) {
        unsigned long long v = base[i];
        best = v > best ? v : best;
    }
    sb[tid] = best;
    __syncthreads();
    #pragma unroll
    for (int s = 128; s > 0; s >>= 1) {
        if (tid < s) {
            unsigned long long o = sb[tid + s];
            if (o > sb[tid]) sb[tid] = o;
        }
        __syncthreads();
    }
    if (tid == 0) {
        unsigned int ic = (unsigned int)(sb[0] & 0xFFFFFFFFull);
        pred[row] = (float)(~ic);
    }
}

extern "C" void kernel_launch(void* const* d_in, const int* in_sizes, int n_in,
                              void* d_out, int out_size, void* d_ws, size_t ws_size,
                              hipStream_t stream) {
    const int*   q   = (const int*)d_in[0];
    const float* ent = (const float*)d_in[1];
    const float* rel = (const float*)d_in[2];
    float* out = (float*)d_out;
    char*  ws  = (char*)d_ws;

    unsigned short*     hrb   = (unsigned short*)ws;
    float*              hrsq  = (float*)(ws + WS_HRSQ);
    float*              entsq = (float*)(ws + WS_ENTSQ);
    unsigned long long* part  = (unsigned long long*)(ws + WS_PART);
    unsigned short*     entb  = (unsigned short*)(ws + WS_ENTB);
    float* pred = out + (size_t)MM * NE;

    prep_kernel<<<MM, 64, 0, stream>>>(q, ent, rel, hrb, hrsq);

    if (ws_size >= WS_NEED) {
        conv_entsq_kernel<<<12500, 256, 0, stream>>>(ent, entb, entsq);
        gemm_v5<<<8 * NGRP, 256, 0, stream>>>(hrb, entb, hrsq, entsq, out, part);
        reduce_kernel<<<MM, 256, 0, stream>>>(part, pred, NGRP);
    } else {
        entsq_kernel<<<(NE + 3) / 4, 256, 0, stream>>>(ent, entsq);
        gemm_direct_f32<<<8 * NT, 256, 0, stream>>>(hrb, ent, hrsq, entsq, out, part);
        reduce_kernel<<<MM, 256, 0, stream>>>(part, pred, NT);
    }
}